// Round 1
// baseline (233.606 us; speedup 1.0000x reference)
//
#include <hip/hip_runtime.h>

// LayerNorm over last dim W=256 for (B=8, C=128, H=128, W=256) fp32,
// then per-channel affine: out = (x - mean)/sqrt(var+eps) * gain[c] + bias[c].
//
// v3: persistent waves + 2-deep software pipeline.
//  - 2048 blocks x 4 waves = 8192 persistent waves (8 blocks/CU -> full
//    32 waves/CU occupancy), each wave grid-strides over 16 rows.
//  - Next row's float4 load is issued BEFORE the current row's reduction,
//    so the ~1.5k-cycle shuffle/epilogue chain hides HBM latency and every
//    wave keeps a load in flight at all times (v2 paid cold-start latency
//    once per wave per row).
// Memory-bound: 268 MB total traffic, roofline ~43 us at 6.3 TB/s.

#define W_DIM 256
#define C_DIM 128
#define EPS 1e-8f

typedef float f32x4 __attribute__((ext_vector_type(4)));

__global__ __launch_bounds__(256) void tLNv3_kernel(
    const float* __restrict__ inp,
    const float* __restrict__ gain,
    const float* __restrict__ bias,
    float* __restrict__ out,
    const int rows, const int wave_stride)
{
    const int lane = threadIdx.x & 63;
    int row = (int)(blockIdx.x << 2) + (threadIdx.x >> 6);  // 4 waves/block
    if (row >= rows) return;

    const f32x4* __restrict__ in4  = (const f32x4*)inp;
    f32x4* __restrict__       out4 = (f32x4*)out;

    // prologue: first row's data
    f32x4 v = in4[(size_t)row * 64 + lane];

    for (;;) {
        // ---- issue next row's load early (prefetch) ----
        const int  nrow      = row + wave_stride;
        const bool have_next = (nrow < rows);
        f32x4 vn = {};
        if (have_next) vn = in4[(size_t)nrow * 64 + lane];

        // ---- reduce current row (hides the prefetch latency) ----
        float s  = v.x + v.y + v.z + v.w;
        float sq = v.x * v.x + v.y * v.y + v.z * v.z + v.w * v.w;

        #pragma unroll
        for (int off = 1; off < 64; off <<= 1) {
            s  += __shfl_xor(s,  off, 64);
            sq += __shfl_xor(sq, off, 64);
        }

        const float mean = s * (1.0f / (float)W_DIM);
        const float var  = sq * (1.0f / (float)W_DIM) - mean * mean;
        const float rstd = rsqrtf(var + EPS);

        // row = b*C*H + c*H + h ; H=128, C=128
        const int   c = (row >> 7) & (C_DIM - 1);
        const float g = gain[c];
        const float b = bias[c];

        f32x4 o;
        o.x = (v.x - mean) * rstd * g + b;
        o.y = (v.y - mean) * rstd * g + b;
        o.z = (v.z - mean) * rstd * g + b;
        o.w = (v.w - mean) * rstd * g + b;
        out4[(size_t)row * 64 + lane] = o;

        if (!have_next) break;
        v   = vn;
        row = nrow;
    }
}

extern "C" void kernel_launch(void* const* d_in, const int* in_sizes, int n_in,
                              void* d_out, int out_size, void* d_ws, size_t ws_size,
                              hipStream_t stream)
{
    const float* inp  = (const float*)d_in[0];
    const float* gain = (const float*)d_in[1];
    const float* bias = (const float*)d_in[2];
    float* out = (float*)d_out;

    const int rows = in_sizes[0] / W_DIM;   // 131072 rows (in_sizes in elements)

    int blocks = (rows + 3) / 4;
    if (blocks > 2048) blocks = 2048;       // 8 blocks/CU, persistent waves
    const int wave_stride = blocks * 4;     // total waves in flight

    tLNv3_kernel<<<blocks, 256, 0, stream>>>(inp, gain, bias, out, rows, wave_stride);
}

// Round 2
// 228.182 us; speedup vs baseline: 1.0238x; 1.0238x over previous
//
#include <hip/hip_runtime.h>

// LayerNorm over last dim W=256 for (B=8, C=128, H=128, W=256) fp32,
// then per-channel affine: out = (x - mean)/sqrt(var+eps) * gain[c] + bias[c].
//
// v4: 16-lanes-per-row, 4 rows per wave, one-shot waves.
//  - Each lane loads 4 float4 = 16 elems of ONE row -> 4 independent loads,
//    4 KB in flight per wave (4x the MLP of v2/v3's single 1 KB load).
//  - Cross-lane reduction is only 4 butterfly steps over 16 lanes
//    (off = 1,2,4,8) instead of 6 steps over 64 lanes: the serial
//    shuffle chain per row drops 6x.
//  - Rows 4g..4g+3 share one channel c = (g>>5)&127 (4g mod 128 <= 124
//    always), so gain/bias are wave-uniform scalar loads.
//  - One 4-row group per wave, no loop, no conditional loads -> compiler
//    emits precise vmcnt, wave churn provides TLP (v2 structure, which
//    beat the persistent v3).
// Memory-bound: 268 MB total traffic, roofline ~43 us at 6.3 TB/s.

#define W_DIM 256
#define C_DIM 128
#define EPS 1e-8f

typedef float f32x4 __attribute__((ext_vector_type(4)));

__global__ __launch_bounds__(256) void tLNv4_kernel(
    const float* __restrict__ inp,
    const float* __restrict__ gain,
    const float* __restrict__ bias,
    float* __restrict__ out,
    const int rows)
{
    const int lane = threadIdx.x & 63;
    const int sub  = lane & 15;          // lane within its row (16 lanes/row)
    const int quad = lane >> 4;          // which of the wave's 4 rows
    const int grp  = (int)(blockIdx.x << 2) + (threadIdx.x >> 6);  // 4 waves/blk

    const int row = (grp << 2) + quad;
    if (row >= rows) return;

    const f32x4* __restrict__ in4  = (const f32x4*)inp;
    f32x4* __restrict__       out4 = (f32x4*)out;

    // 4 independent 16B loads per lane: elements [16*j + sub] of this row
    const size_t base = (size_t)row * 64 + sub;
    f32x4 v0 = in4[base];
    f32x4 v1 = in4[base + 16];
    f32x4 v2 = in4[base + 32];
    f32x4 v3 = in4[base + 48];

    // per-lane partial sums over 16 elements
    float s = (v0.x + v0.y) + (v0.z + v0.w)
            + (v1.x + v1.y) + (v1.z + v1.w)
            + (v2.x + v2.y) + (v2.z + v2.w)
            + (v3.x + v3.y) + (v3.z + v3.w);
    float sq = v0.x * v0.x;
    sq = fmaf(v0.y, v0.y, sq); sq = fmaf(v0.z, v0.z, sq); sq = fmaf(v0.w, v0.w, sq);
    sq = fmaf(v1.x, v1.x, sq); sq = fmaf(v1.y, v1.y, sq);
    sq = fmaf(v1.z, v1.z, sq); sq = fmaf(v1.w, v1.w, sq);
    sq = fmaf(v2.x, v2.x, sq); sq = fmaf(v2.y, v2.y, sq);
    sq = fmaf(v2.z, v2.z, sq); sq = fmaf(v2.w, v2.w, sq);
    sq = fmaf(v3.x, v3.x, sq); sq = fmaf(v3.y, v3.y, sq);
    sq = fmaf(v3.z, v3.z, sq); sq = fmaf(v3.w, v3.w, sq);

    // 4-step butterfly within each 16-lane row group
    #pragma unroll
    for (int off = 1; off < 16; off <<= 1) {
        s  += __shfl_xor(s,  off, 64);
        sq += __shfl_xor(sq, off, 64);
    }

    const float mean = s * (1.0f / (float)W_DIM);
    const float var  = sq * (1.0f / (float)W_DIM) - mean * mean;
    const float rstd = rsqrtf(var + EPS);

    // channel is uniform across the wave's 4 rows: c = (4*grp+q)>>7 & 127
    const int   c = (grp >> 5) & (C_DIM - 1);
    const float g = gain[c];
    const float b = bias[c];

    const float a  = rstd * g;           // out = v*a + bb
    const float bb = b - mean * a;

    f32x4 o0, o1, o2, o3;
    o0.x = fmaf(v0.x, a, bb); o0.y = fmaf(v0.y, a, bb);
    o0.z = fmaf(v0.z, a, bb); o0.w = fmaf(v0.w, a, bb);
    o1.x = fmaf(v1.x, a, bb); o1.y = fmaf(v1.y, a, bb);
    o1.z = fmaf(v1.z, a, bb); o1.w = fmaf(v1.w, a, bb);
    o2.x = fmaf(v2.x, a, bb); o2.y = fmaf(v2.y, a, bb);
    o2.z = fmaf(v2.z, a, bb); o2.w = fmaf(v2.w, a, bb);
    o3.x = fmaf(v3.x, a, bb); o3.y = fmaf(v3.y, a, bb);
    o3.z = fmaf(v3.z, a, bb); o3.w = fmaf(v3.w, a, bb);

    out4[base]      = o0;
    out4[base + 16] = o1;
    out4[base + 32] = o2;
    out4[base + 48] = o3;
}

extern "C" void kernel_launch(void* const* d_in, const int* in_sizes, int n_in,
                              void* d_out, int out_size, void* d_ws, size_t ws_size,
                              hipStream_t stream)
{
    const float* inp  = (const float*)d_in[0];
    const float* gain = (const float*)d_in[1];
    const float* bias = (const float*)d_in[2];
    float* out = (float*)d_out;

    const int rows   = in_sizes[0] / W_DIM;     // 131072
    const int groups = (rows + 3) / 4;          // 4-row groups, one per wave
    const int blocks = (groups + 3) / 4;        // 4 waves per block -> 8192

    tLNv4_kernel<<<blocks, 256, 0, stream>>>(inp, gain, bias, out, rows);
}